// Round 1
// baseline (1674.028 us; speedup 1.0000x reference)
//
#include <hip/hip_runtime.h>

#define EPSB 1e-5f

// Shapes: N=2, C=256, Cc=64, H=W=48 (HW=2304), OH=OW=96 (OHW=9216),
// FH=FW=192 (FHW=36864), K=5 (KK=25), UP=2 (UU=4), KCH=100.

// ---------------- K1: 1x1 compress conv + BN + ReLU ----------------
__global__ __launch_bounds__(256) void k_compress(
    const float* __restrict__ x, const float* __restrict__ w,
    const float* __restrict__ g, const float* __restrict__ b,
    const float* __restrict__ m, const float* __restrict__ v,
    float* __restrict__ out) {
  int idx = blockIdx.x * 256 + threadIdx.x;   // 2*64*2304
  int pix = idx % 2304;
  int t   = idx / 2304;
  int co  = t % 64, n = t / 64;
  const float* xp = x + n * 256 * 2304 + pix;
  const float* wp = w + co * 256;
  float acc = 0.f;
  for (int ci = 0; ci < 256; ++ci) acc = fmaf(xp[ci * 2304], wp[ci], acc);
  float inv = g[co] / sqrtf(v[co] + EPSB);
  float val = acc * inv + (b[co] - m[co] * inv);
  out[idx] = fmaxf(val, 0.f);
}

// ---------------- K2: 3x3 dilated (dil=2, pad=2) conv + BN + ReLU ----------------
__global__ __launch_bounds__(256) void k_ke1(
    const float* __restrict__ comp, const float* __restrict__ w,
    const float* __restrict__ g, const float* __restrict__ b,
    const float* __restrict__ m, const float* __restrict__ v,
    float* __restrict__ out) {
  int idx = blockIdx.x * 256 + threadIdx.x;   // 2*64*2304
  int pix = idx % 2304;
  int t   = idx / 2304;
  int co  = t % 64, n = t / 64;
  int y = pix / 48, x0 = pix % 48;
  const float* cp = comp + n * 64 * 2304;
  const float* wp = w + co * 64 * 9;
  float acc = 0.f;
  for (int ci = 0; ci < 64; ++ci) {
    const float* cc = cp + ci * 2304;
    const float* wc = wp + ci * 9;
#pragma unroll
    for (int i = 0; i < 3; ++i) {
      int yy = y + 2 * i - 2;
      if (yy < 0 || yy >= 48) continue;
#pragma unroll
      for (int j = 0; j < 3; ++j) {
        int xx = x0 + 2 * j - 2;
        if (xx < 0 || xx >= 48) continue;
        acc = fmaf(cc[yy * 48 + xx], wc[i * 3 + j], acc);
      }
    }
  }
  float inv = g[co] / sqrtf(v[co] + EPSB);
  float val = acc * inv + (b[co] - m[co] * inv);
  out[idx] = fmaxf(val, 0.f);
}

// ---------------- K3: 3x3 conv (pad=1) to 100 channels ----------------
__global__ __launch_bounds__(256) void k_ke2(
    const float* __restrict__ k1, const float* __restrict__ w,
    float* __restrict__ out) {
  int idx = blockIdx.x * 256 + threadIdx.x;   // 2*100*2304
  int pix = idx % 2304;
  int t   = idx / 2304;
  int o   = t % 100, n = t / 100;
  int y = pix / 48, x0 = pix % 48;
  const float* kp = k1 + n * 64 * 2304;
  const float* wp = w + o * 64 * 9;
  float acc = 0.f;
  for (int ci = 0; ci < 64; ++ci) {
    const float* cc = kp + ci * 2304;
    const float* wc = wp + ci * 9;
#pragma unroll
    for (int i = 0; i < 3; ++i) {
      int yy = y + i - 1;
      if (yy < 0 || yy >= 48) continue;
#pragma unroll
      for (int j = 0; j < 3; ++j) {
        int xx = x0 + j - 1;
        if (xx < 0 || xx >= 48) continue;
        acc = fmaf(cc[yy * 48 + xx], wc[i * 3 + j], acc);
      }
    }
  }
  out[idx] = acc;
}

// ---------------- K4: softmax over 25 taps per (n,u,pix), in place ----------------
__global__ __launch_bounds__(256) void k_softmax(float* __restrict__ kern) {
  int idx = blockIdx.x * 256 + threadIdx.x;   // 2*4*2304
  int pix = idx % 2304;
  int t   = idx / 2304;
  int u = t % 4, n = t / 4;
  float* p = kern + (n * 100 + u * 25) * 2304 + pix;
  float vals[25], mx = -3.4e38f;
#pragma unroll
  for (int k = 0; k < 25; ++k) { vals[k] = p[k * 2304]; mx = fmaxf(mx, vals[k]); }
  float s = 0.f;
#pragma unroll
  for (int k = 0; k < 25; ++k) { vals[k] = expf(vals[k] - mx); s += vals[k]; }
  float r = 1.f / s;
#pragma unroll
  for (int k = 0; k < 25; ++k) p[k * 2304] = vals[k] * r;
}

// ---------------- K5: bilinear 48->96 upsample, transposed out [n][pos][ch] ----------------
__global__ __launch_bounds__(256) void k_bilin(const float* __restrict__ kern,
                                               float* __restrict__ kup_t) {
  int idx = blockIdx.x * 256 + threadIdx.x;   // 2*9216*100
  int ch  = idx % 100;
  int t   = idx / 100;
  int pos = t % 9216, n = t / 9216;
  int Y = pos / 96, X = pos % 96;
  float sy = fminf(fmaxf(Y * 0.5f - 0.25f, 0.f), 47.f);
  int y0 = (int)sy; int y1 = min(y0 + 1, 47); float wy = sy - (float)y0;
  float sx = fminf(fmaxf(X * 0.5f - 0.25f, 0.f), 47.f);
  int x0 = (int)sx; int x1 = min(x0 + 1, 47); float wx = sx - (float)x0;
  const float* p = kern + (n * 100 + ch) * 2304;
  float v00 = p[y0 * 48 + x0], v01 = p[y0 * 48 + x1];
  float v10 = p[y1 * 48 + x0], v11 = p[y1 * 48 + x1];
  float top = v00 * (1.f - wx) + v01 * wx;
  float bot = v10 * (1.f - wx) + v11 * wx;
  kup_t[idx] = top * (1.f - wy) + bot * wy;
}

// ---------------- K6: fused reassembly + pixel-shuffle remap + 1x1 proj + BN + ReLU ----
// Block: one (n, Y, 32-wide X tile). Thread t = final channel c2.
// final[n,c2,Y,X] = sum_k x[n, c_map, (Y/2 + kh-2)/2, (X/2 + kw-2)/2] * kup[n, u, k, Y/2, X/2]
//   with u = c2>>6, c_map = ((c2&63)<<2) | (Y&1)<<1 | (X&1)
__global__ __launch_bounds__(256) void k_reassemble_proj(
    const float* __restrict__ x, const float* __restrict__ kup_t,
    const float* __restrict__ pw, const float* __restrict__ g,
    const float* __restrict__ b, const float* __restrict__ m,
    const float* __restrict__ v, float* __restrict__ out) {
  __shared__ float fin[256 * 32];
  int blk = blockIdx.x;            // 2304 = 2 * 192 * 6
  int n = blk / 1152;
  int r = blk % 1152;
  int Y = r / 6;
  int X0 = (r % 6) * 32;
  int t = threadIdx.x;
  int u = t >> 6, ch = t & 63;
  int p = Y & 1, y = Y >> 1;
  const float* xb = x + n * 256 * 2304;
  const float* kb = kup_t + (size_t)(n * 9216 + y * 96) * 100 + u * 25;

  // ---- phase 1: build final[c2][32 px] tile in LDS ----
  for (int px2 = 0; px2 < 16; ++px2) {
    int xs = (X0 >> 1) + px2;        // 96-res x coordinate
    const float* kp = kb + xs * 100; // 25 contiguous softmax weights (wave-uniform)
    float kv[25];
#pragma unroll
    for (int k = 0; k < 25; ++k) kv[k] = kp[k];
#pragma unroll
    for (int q = 0; q < 2; ++q) {
      int c = (ch << 2) | (p << 1) | q;
      const float* xc = xb + c * 2304;
      float acc = 0.f;
#pragma unroll
      for (int kh = 0; kh < 5; ++kh) {
        int yy = y + kh - 2;
        if (yy < 0 || yy >= 96) continue;
        const float* xr = xc + (yy >> 1) * 48;
#pragma unroll
        for (int kw = 0; kw < 5; ++kw) {
          int xx = xs + kw - 2;
          if (xx < 0 || xx >= 96) continue;
          acc = fmaf(xr[xx >> 1], kv[kh * 5 + kw], acc);
        }
      }
      fin[t * 32 + px2 * 2 + q] = acc;
    }
  }
  __syncthreads();

  // ---- phase 2: 1x1 proj GEMM: out[t, px] = sum_ci pw[t,ci] * fin[ci,px] ----
  float acc[32];
#pragma unroll
  for (int i = 0; i < 32; ++i) acc[i] = 0.f;
  const float* wp = pw + t * 256;
  for (int ci = 0; ci < 256; ++ci) {
    float wv = wp[ci];
    const float4* fr = (const float4*)&fin[ci * 32];
#pragma unroll
    for (int i = 0; i < 8; ++i) {
      float4 f = fr[i];
      acc[4 * i + 0] = fmaf(f.x, wv, acc[4 * i + 0]);
      acc[4 * i + 1] = fmaf(f.y, wv, acc[4 * i + 1]);
      acc[4 * i + 2] = fmaf(f.z, wv, acc[4 * i + 2]);
      acc[4 * i + 3] = fmaf(f.w, wv, acc[4 * i + 3]);
    }
  }
  float inv = g[t] / sqrtf(v[t] + EPSB);
  float bb  = b[t] - m[t] * inv;
  __syncthreads();
#pragma unroll
  for (int i = 0; i < 32; ++i) fin[t * 32 + i] = fmaxf(acc[i] * inv + bb, 0.f);
  __syncthreads();

  // ---- coalesced store ----
  float* ob = out + (size_t)n * 256 * 36864 + Y * 192 + X0;
  int px = t & 31;
  int w5 = t >> 5;
  for (int i = 0; i < 32; ++i) {
    int co = i * 8 + w5;
    ob[(size_t)co * 36864 + px] = fin[co * 32 + px];
  }
}

extern "C" void kernel_launch(void* const* d_in, const int* in_sizes, int n_in,
                              void* d_out, int out_size, void* d_ws, size_t ws_size,
                              hipStream_t stream) {
  const float* x   = (const float*)d_in[0];
  const float* cw  = (const float*)d_in[1];
  const float* g1  = (const float*)d_in[2];
  const float* b1  = (const float*)d_in[3];
  const float* m1  = (const float*)d_in[4];
  const float* v1  = (const float*)d_in[5];
  const float* k1w = (const float*)d_in[6];
  const float* gk  = (const float*)d_in[7];
  const float* bk  = (const float*)d_in[8];
  const float* mk  = (const float*)d_in[9];
  const float* vk  = (const float*)d_in[10];
  const float* k2w = (const float*)d_in[11];
  const float* pw  = (const float*)d_in[12];
  const float* g2  = (const float*)d_in[13];
  const float* b2  = (const float*)d_in[14];
  const float* m2  = (const float*)d_in[15];
  const float* v2  = (const float*)d_in[16];
  float* out = (float*)d_out;
  float* ws  = (float*)d_ws;

  float* comp = ws;                 // 294912 floats
  float* k1b  = ws + 294912;        // 294912
  float* kern = ws + 589824;        // 460800
  float* kupt = ws + 1050624;       // 1843200  (end: 2893824 floats = 11.6 MB)

  k_compress<<<1152, 256, 0, stream>>>(x, cw, g1, b1, m1, v1, comp);
  k_ke1<<<1152, 256, 0, stream>>>(comp, k1w, gk, bk, mk, vk, k1b);
  k_ke2<<<1800, 256, 0, stream>>>(k1b, k2w, kern);
  k_softmax<<<72, 256, 0, stream>>>(kern);
  k_bilin<<<7200, 256, 0, stream>>>(kern, kupt);
  k_reassemble_proj<<<2304, 256, 0, stream>>>(x, kupt, pw, g2, b2, m2, v2, out);
}

// Round 2
// 272.406 us; speedup vs baseline: 6.1453x; 6.1453x over previous
//
#include <hip/hip_runtime.h>

#define EPSB 1e-5f

typedef __attribute__((ext_vector_type(8))) short bf16x8;
typedef __attribute__((ext_vector_type(4))) float f32x4;

__device__ __forceinline__ unsigned short f2b(float f) {
  union { float f; unsigned u; } cv; cv.f = f;
  unsigned r = cv.u + 0x7FFFu + ((cv.u >> 16) & 1u);
  return (unsigned short)(r >> 16);
}

// ---------------- K0: convert proj weights to bf16 ----------------
__global__ __launch_bounds__(256) void k_cvt(const float* __restrict__ pw,
                                             unsigned short* __restrict__ pwb) {
  int i = blockIdx.x * 256 + threadIdx.x;   // 65536
  pwb[i] = f2b(pw[i]);
}

// ---------------- K1: 1x1 compress conv + BN + ReLU -> padded (pad=2) ----------------
// 2 co x 4 pix per thread; threads = 2*32*576 = 36864
__global__ __launch_bounds__(256) void k_compress(
    const float* __restrict__ x, const float* __restrict__ w,
    const float* __restrict__ g, const float* __restrict__ b,
    const float* __restrict__ m, const float* __restrict__ v,
    float* __restrict__ comp_p) {
  int idx = blockIdx.x * 256 + threadIdx.x;
  int p4 = idx % 576;
  int t2 = idx / 576;           // 0..63
  int co2 = (t2 & 31) * 2;
  int n = t2 >> 5;
  int pix = p4 * 4;
  const float* xp = x + (size_t)n * 256 * 2304 + pix;
  float acc[2][4] = {};
  for (int ci = 0; ci < 256; ++ci) {
    float4 xv = *(const float4*)(xp + (size_t)ci * 2304);
#pragma unroll
    for (int a = 0; a < 2; ++a) {
      float wv = w[(co2 + a) * 256 + ci];
      acc[a][0] = fmaf(xv.x, wv, acc[a][0]);
      acc[a][1] = fmaf(xv.y, wv, acc[a][1]);
      acc[a][2] = fmaf(xv.z, wv, acc[a][2]);
      acc[a][3] = fmaf(xv.w, wv, acc[a][3]);
    }
  }
  int y = pix / 48, x0 = pix % 48;
#pragma unroll
  for (int a = 0; a < 2; ++a) {
    int co = co2 + a;
    float inv = g[co] / sqrtf(v[co] + EPSB);
    float bb = b[co] - m[co] * inv;
    float* op = comp_p + ((size_t)(n * 64 + co) * 52 + (y + 2)) * 52 + (x0 + 2);
#pragma unroll
    for (int q = 0; q < 4; ++q) op[q] = fmaxf(acc[a][q] * inv + bb, 0.f);
  }
}

// ---------------- K2: 3x3 dil=2 conv + BN + ReLU, padded in (2) / out (1) ----------------
// 2 co x 4 pix; threads = 2*32*576 = 36864
__global__ __launch_bounds__(256) void k_ke1(
    const float* __restrict__ comp_p, const float* __restrict__ w,
    const float* __restrict__ g, const float* __restrict__ b,
    const float* __restrict__ m, const float* __restrict__ v,
    float* __restrict__ k1_p) {
  int idx = blockIdx.x * 256 + threadIdx.x;
  int p4 = idx % 576;
  int t2 = idx / 576;
  int co2 = (t2 & 31) * 2;
  int n = t2 >> 5;
  int pix = p4 * 4;
  int y = pix / 48, x0 = pix % 48;
  const float* cp = comp_p + (size_t)n * 64 * 2704 + (size_t)y * 52 + x0;
  float acc[2][4] = {};
  for (int ci = 0; ci < 64; ++ci) {
    const float* base = cp + (size_t)ci * 2704;
    float c8[3][8];
#pragma unroll
    for (int i = 0; i < 3; ++i) {
      float4 va = *(const float4*)(base + i * 104);
      float4 vb = *(const float4*)(base + i * 104 + 4);
      c8[i][0] = va.x; c8[i][1] = va.y; c8[i][2] = va.z; c8[i][3] = va.w;
      c8[i][4] = vb.x; c8[i][5] = vb.y; c8[i][6] = vb.z; c8[i][7] = vb.w;
    }
#pragma unroll
    for (int a = 0; a < 2; ++a) {
      const float* wc = w + ((co2 + a) * 64 + ci) * 9;
#pragma unroll
      for (int i = 0; i < 3; ++i)
#pragma unroll
        for (int j = 0; j < 3; ++j) {
          float wv = wc[i * 3 + j];
#pragma unroll
          for (int q = 0; q < 4; ++q)
            acc[a][q] = fmaf(c8[i][2 * j + q], wv, acc[a][q]);
        }
    }
  }
#pragma unroll
  for (int a = 0; a < 2; ++a) {
    int co = co2 + a;
    float inv = g[co] / sqrtf(v[co] + EPSB);
    float bb = b[co] - m[co] * inv;
    float* op = k1_p + ((size_t)(n * 64 + co) * 50 + (y + 1)) * 50 + (x0 + 1);
#pragma unroll
    for (int q = 0; q < 4; ++q) op[q] = fmaxf(acc[a][q] * inv + bb, 0.f);
  }
}

// ---------------- K3: 3x3 conv (pad=1) to 100 ch ----------------
// 2 co x 4 pix; threads = 2*50*576 = 57600
__global__ __launch_bounds__(256) void k_ke2(
    const float* __restrict__ k1_p, const float* __restrict__ w,
    float* __restrict__ kern) {
  int idx = blockIdx.x * 256 + threadIdx.x;
  int p4 = idx % 576;
  int t2 = idx / 576;           // 0..99
  int co2 = (t2 % 50) * 2;
  int n = t2 / 50;
  int pix = p4 * 4;
  int y = pix / 48, x0 = pix % 48;
  const float* kp = k1_p + (size_t)n * 64 * 2500 + (size_t)y * 50 + x0;
  float acc[2][4] = {};
  for (int ci = 0; ci < 64; ++ci) {
    const float* base = kp + (size_t)ci * 2500;
    float c8[3][8];
#pragma unroll
    for (int i = 0; i < 3; ++i) {
      float4 va = *(const float4*)(base + i * 50);
      float4 vb = *(const float4*)(base + i * 50 + 4);
      c8[i][0] = va.x; c8[i][1] = va.y; c8[i][2] = va.z; c8[i][3] = va.w;
      c8[i][4] = vb.x; c8[i][5] = vb.y; c8[i][6] = vb.z; c8[i][7] = vb.w;
    }
#pragma unroll
    for (int a = 0; a < 2; ++a) {
      const float* wc = w + ((co2 + a) * 64 + ci) * 9;
#pragma unroll
      for (int i = 0; i < 3; ++i)
#pragma unroll
        for (int j = 0; j < 3; ++j) {
          float wv = wc[i * 3 + j];
#pragma unroll
          for (int q = 0; q < 4; ++q)
            acc[a][q] = fmaf(c8[i][j + q], wv, acc[a][q]);
        }
    }
  }
#pragma unroll
  for (int a = 0; a < 2; ++a) {
    float* op = kern + ((size_t)n * 100 + co2 + a) * 2304 + pix;
#pragma unroll
    for (int q = 0; q < 4; ++q) op[q] = acc[a][q];
  }
}

// ---------------- K4: softmax over 25 taps per (n,u,pix) ----------------
__global__ __launch_bounds__(256) void k_softmax(float* __restrict__ kern) {
  int idx = blockIdx.x * 256 + threadIdx.x;   // 18432
  int pix = idx % 2304;
  int t   = idx / 2304;
  int u = t % 4, n = t / 4;
  float* p = kern + ((size_t)n * 100 + u * 25) * 2304 + pix;
  float vals[25], mx = -3.4e38f;
#pragma unroll
  for (int k = 0; k < 25; ++k) { vals[k] = p[k * 2304]; mx = fmaxf(mx, vals[k]); }
  float s = 0.f;
#pragma unroll
  for (int k = 0; k < 25; ++k) { vals[k] = expf(vals[k] - mx); s += vals[k]; }
  float r = 1.f / s;
#pragma unroll
  for (int k = 0; k < 25; ++k) p[k * 2304] = vals[k] * r;
}

// ---------------- K5: bilinear upsample + fold 25 taps -> 9 source-pixel weights ----
// layout out: [n][y96][w2][u][9]
__global__ __launch_bounds__(256) void k_w9(const float* __restrict__ kern,
                                            float* __restrict__ w9) {
  int idx = blockIdx.x * 256 + threadIdx.x;  // 73728
  int w2 = idx % 96;
  int t3 = idx / 96;
  int y96 = t3 % 96;
  int t4 = t3 / 96;
  int u = t4 & 3;
  int n = t4 >> 2;
  float syf = fminf(fmaxf(y96 * 0.5f - 0.25f, 0.f), 47.f);
  int y0 = (int)syf; int y1 = min(y0 + 1, 47); float wy = syf - (float)y0;
  float sxf = fminf(fmaxf(w2 * 0.5f - 0.25f, 0.f), 47.f);
  int x0 = (int)sxf; int x1 = min(x0 + 1, 47); float wx = sxf - (float)x0;
  const float* kp = kern + ((size_t)n * 100 + u * 25) * 2304;
  int o00 = y0 * 48 + x0, o01 = y0 * 48 + x1, o10 = y1 * 48 + x0, o11 = y1 * 48 + x1;
  float bl[5][5];
#pragma unroll
  for (int kh = 0; kh < 5; ++kh) {
    bool vy = (unsigned)(y96 + kh - 2) < 96u;
#pragma unroll
    for (int kw = 0; kw < 5; ++kw) {
      bool vx = (unsigned)(w2 + kw - 2) < 96u;
      const float* c = kp + (size_t)(kh * 5 + kw) * 2304;
      float tp = c[o00] * (1.f - wx) + c[o01] * wx;
      float bt = c[o10] * (1.f - wx) + c[o11] * wx;
      float vb = tp * (1.f - wy) + bt * wy;
      bl[kh][kw] = (vy && vx) ? vb : 0.f;
    }
  }
  int py = y96 & 1, px_ = w2 & 1;
  float cc0[5], cc1[5], cc2[5];
#pragma unroll
  for (int kh = 0; kh < 5; ++kh) {
    cc0[kh] = px_ ? bl[kh][0] : bl[kh][0] + bl[kh][1];
    cc1[kh] = px_ ? bl[kh][1] + bl[kh][2] : bl[kh][2] + bl[kh][3];
    cc2[kh] = px_ ? bl[kh][3] + bl[kh][4] : bl[kh][4];
  }
  float* op = w9 + (((size_t)(n * 96 + y96) * 96 + w2) * 4 + u) * 9;
  op[0] = py ? cc0[0] : cc0[0] + cc0[1];
  op[1] = py ? cc1[0] : cc1[0] + cc1[1];
  op[2] = py ? cc2[0] : cc2[0] + cc2[1];
  op[3] = py ? cc0[1] + cc0[2] : cc0[2] + cc0[3];
  op[4] = py ? cc1[1] + cc1[2] : cc1[2] + cc1[3];
  op[5] = py ? cc2[1] + cc2[2] : cc2[2] + cc2[3];
  op[6] = py ? cc0[3] + cc0[4] : cc0[4];
  op[7] = py ? cc1[3] + cc1[4] : cc1[4];
  op[8] = py ? cc2[3] + cc2[4] : cc2[4];
}

// ---------------- K6: fused reassembly + remap + MFMA 1x1 proj + BN + ReLU ----------
// block = (n, Y in 192-res, 32-wide X tile); final channel c2: u=c2>>6,
// c = ((c2&63)<<2)|((Y&1)<<1)|(X&1); source pixels: 3x3 around (Y>>2, (X>>1)>>1)
__global__ __launch_bounds__(256) void k_reassemble_proj(
    const float* __restrict__ x, const float* __restrict__ w9,
    const unsigned short* __restrict__ pwb, const float* __restrict__ g,
    const float* __restrict__ b, const float* __restrict__ m,
    const float* __restrict__ v, float* __restrict__ out) {
  __shared__ float xls[128 * 33];          // [c_local][3 rows * 11 cols] stride 33
  __shared__ float w9s[576];               // [w2_local][u][9]
  __shared__ unsigned short finT[32 * 256];// [px][ci] bf16, XOR-swizzled blocks of 8

  int blk = blockIdx.x;                    // 2304 = 2 * 192 * 6
  int n  = blk / 1152;
  int r  = blk % 1152;
  int Y  = r / 6;
  int X0 = (r % 6) * 32;
  int t  = threadIdx.x;

  int p    = Y & 1;
  int y96  = Y >> 1;
  int y48  = Y >> 2;
  int w0   = X0 >> 1;                      // 96-res col base (16-aligned)
  int x480 = w0 >> 1;                      // 48-res col base

  // stage 9-tap weights (576 contiguous floats)
  const float* wsrc = w9 + ((size_t)(n * 96 + y96) * 96 + w0) * 36;
  for (int f = t; f < 576; f += 256) w9s[f] = wsrc[f];

  // stage x: 128 needed channels x 3 rows x 11 cols (clamped; weights 0 there)
  const float* xb = x + (size_t)n * 256 * 2304;
  for (int f = t; f < 128 * 33; f += 256) {
    int cl  = f / 33;
    int rc  = f - cl * 33;
    int syi = rc / 11;
    int col = rc - syi * 11;
    int c   = (cl >> 1) * 4 + p * 2 + (cl & 1);
    int sy  = min(max(y48 + syi - 1, 0), 47);
    int sx  = min(max(x480 - 1 + col, 0), 47);
    xls[f] = xb[(size_t)c * 2304 + sy * 48 + sx];
  }
  __syncthreads();

  // ---- phase 1: 9-tap reassembly, write finT bf16 swizzled ----
  {
    int ch = t & 63;
    int u  = t >> 6;
    const float* xc0 = &xls[(ch * 2 + 0) * 33];
    const float* xc1 = &xls[(ch * 2 + 1) * 33];
    float xw0[9], xw1[9];
#pragma unroll
    for (int ry = 0; ry < 3; ++ry)
#pragma unroll
      for (int cx = 0; cx < 3; ++cx) {
        xw0[ry * 3 + cx] = xc0[ry * 11 + cx];
        xw1[ry * 3 + cx] = xc1[ry * 11 + cx];
      }
    int cb = t >> 3, crr = t & 7;
#pragma unroll
    for (int j = 0; j < 16; ++j) {
      if (j >= 2 && (j & 1) == 0) {
        int nc = (j >> 1) + 2;
#pragma unroll
        for (int ry = 0; ry < 3; ++ry) {
          xw0[ry*3+0] = xw0[ry*3+1]; xw0[ry*3+1] = xw0[ry*3+2]; xw0[ry*3+2] = xc0[ry*11+nc];
          xw1[ry*3+0] = xw1[ry*3+1]; xw1[ry*3+1] = xw1[ry*3+2]; xw1[ry*3+2] = xc1[ry*11+nc];
        }
      }
      const float* wt = &w9s[j * 36 + u * 9];
      float a0 = 0.f, a1 = 0.f;
#pragma unroll
      for (int k9 = 0; k9 < 9; ++k9) {
        float wv = wt[k9];
        a0 = fmaf(xw0[k9], wv, a0);
        a1 = fmaf(xw1[k9], wv, a1);
      }
      int px0 = 2 * j, px1 = 2 * j + 1;
      finT[px0 * 256 + ((cb ^ (px0 & 7)) * 8 + crr)] = f2b(a0);
      finT[px1 * 256 + ((cb ^ (px1 & 7)) * 8 + crr)] = f2b(a1);
    }
  }
  __syncthreads();

  // ---- phase 2: MFMA GEMM  out[256 o][32 px] = pw[256x256] * fin[256][32] ----
  int wv_ = t >> 6, l = t & 63;
  int l15 = l & 15, lg = l >> 4;
  int obase = wv_ * 64;
  f32x4 acc[4][2];
#pragma unroll
  for (int mt = 0; mt < 4; ++mt)
#pragma unroll
    for (int nt = 0; nt < 2; ++nt) acc[mt][nt] = (f32x4){0.f, 0.f, 0.f, 0.f};

#pragma unroll
  for (int kbi = 0; kbi < 8; ++kbi) {
    int kb = kbi * 32;
    int cbk = (kb >> 3) + lg;
    bf16x8 bfr[2];
#pragma unroll
    for (int nt = 0; nt < 2; ++nt) {
      int row = nt * 16 + l15;
      int off = row * 256 + ((cbk ^ (row & 7)) * 8);
      bfr[nt] = *(const bf16x8*)&finT[off];
    }
#pragma unroll
    for (int mt = 0; mt < 4; ++mt) {
      bf16x8 afr = *(const bf16x8*)(pwb + (size_t)(obase + mt * 16 + l15) * 256 + kb + lg * 8);
#pragma unroll
      for (int nt = 0; nt < 2; ++nt)
        acc[mt][nt] = __builtin_amdgcn_mfma_f32_16x16x32_bf16(afr, bfr[nt], acc[mt][nt], 0, 0, 0);
    }
  }

  size_t outb = (size_t)n * 256 * 36864 + (size_t)Y * 192 + X0;
#pragma unroll
  for (int mt = 0; mt < 4; ++mt) {
#pragma unroll
    for (int r4 = 0; r4 < 4; ++r4) {
      int o = obase + mt * 16 + lg * 4 + r4;
      float inv = g[o] / sqrtf(v[o] + EPSB);
      float bb  = b[o] - m[o] * inv;
#pragma unroll
      for (int nt = 0; nt < 2; ++nt) {
        float val = acc[mt][nt][r4] * inv + bb;
        out[outb + (size_t)o * 36864 + nt * 16 + l15] = fmaxf(val, 0.f);
      }
    }
  }
}

extern "C" void kernel_launch(void* const* d_in, const int* in_sizes, int n_in,
                              void* d_out, int out_size, void* d_ws, size_t ws_size,
                              hipStream_t stream) {
  const float* x   = (const float*)d_in[0];
  const float* cw  = (const float*)d_in[1];
  const float* g1  = (const float*)d_in[2];
  const float* b1  = (const float*)d_in[3];
  const float* m1  = (const float*)d_in[4];
  const float* v1  = (const float*)d_in[5];
  const float* k1w = (const float*)d_in[6];
  const float* gk  = (const float*)d_in[7];
  const float* bk  = (const float*)d_in[8];
  const float* mk  = (const float*)d_in[9];
  const float* vk  = (const float*)d_in[10];
  const float* k2w = (const float*)d_in[11];
  const float* pw  = (const float*)d_in[12];
  const float* g2  = (const float*)d_in[13];
  const float* b2  = (const float*)d_in[14];
  const float* m2  = (const float*)d_in[15];
  const float* v2  = (const float*)d_in[16];
  float* out = (float*)d_out;
  float* ws  = (float*)d_ws;

  float* comp_p = ws;                         // 2*64*52*52 = 346112
  float* k1_p   = ws + 346112;                // 2*64*50*50 = 320000
  float* kern   = ws + 666112;                // 2*100*2304 = 460800
  float* w9     = ws + 1126912;               // 2*96*96*36 = 663552
  unsigned short* pwb = (unsigned short*)(ws + 1790464);  // 65536 bf16

  hipMemsetAsync(comp_p, 0, 346112 * sizeof(float), stream);
  hipMemsetAsync(k1_p, 0, 320000 * sizeof(float), stream);

  k_cvt<<<256, 256, 0, stream>>>(pw, pwb);
  k_compress<<<144, 256, 0, stream>>>(x, cw, g1, b1, m1, v1, comp_p);
  k_ke1<<<144, 256, 0, stream>>>(comp_p, k1w, gk, bk, mk, vk, k1_p);
  k_ke2<<<225, 256, 0, stream>>>(k1_p, k2w, kern);
  k_softmax<<<72, 256, 0, stream>>>(kern);
  k_w9<<<288, 256, 0, stream>>>(kern, w9);
  k_reassemble_proj<<<2304, 256, 0, stream>>>(x, w9, pwb, g2, b2, m2, v2, out);
}

// Round 3
// 211.140 us; speedup vs baseline: 7.9285x; 1.2902x over previous
//
#include <hip/hip_runtime.h>

#define EPSB 1e-5f

typedef __attribute__((ext_vector_type(8))) short bf16x8;
typedef __attribute__((ext_vector_type(4))) float f32x4;

__device__ __forceinline__ unsigned short f2b(float f) {
  union { float f; unsigned u; } cv; cv.f = f;
  unsigned r = cv.u + 0x7FFFu + ((cv.u >> 16) & 1u);
  return (unsigned short)(r >> 16);
}

// ---------------- K_prep: weight conversions/transposes + BN scale/bias ----------
__global__ __launch_bounds__(256) void k_prep(
    const float* __restrict__ pw, const float* __restrict__ cw,
    const float* __restrict__ k1w, const float* __restrict__ k2w,
    const float* __restrict__ g1, const float* __restrict__ b1,
    const float* __restrict__ m1, const float* __restrict__ v1,
    const float* __restrict__ gk, const float* __restrict__ bk,
    const float* __restrict__ mk, const float* __restrict__ vk,
    const float* __restrict__ g2, const float* __restrict__ b2,
    const float* __restrict__ m2, const float* __restrict__ v2,
    unsigned short* __restrict__ pwb, unsigned short* __restrict__ wcb_t,
    unsigned short* __restrict__ wt1, unsigned short* __restrict__ wt2,
    float* __restrict__ sb1, float* __restrict__ sbk, float* __restrict__ sb2) {
  int i = blockIdx.x * 256 + threadIdx.x;
  if (i < 65536) pwb[i] = f2b(pw[i]);
  int j = i - 65536;
  if (j >= 0 && j < 16384) { int ci = j >> 6, co = j & 63; wcb_t[j] = f2b(cw[co * 256 + ci]); }
  int a = i - 81920;
  if (a >= 0 && a < 36864) {
    int co = a / 576, k = a % 576, tap = k >> 6, ci = k & 63;
    wt1[a] = f2b(k1w[co * 576 + ci * 9 + tap]);
  }
  int c2 = i - 118784;
  if (c2 >= 0 && c2 < 73728) {
    int co = c2 / 576, k = c2 % 576, tap = k >> 6, ci = k & 63;
    wt2[c2] = (co < 100) ? f2b(k2w[co * 576 + ci * 9 + tap]) : (unsigned short)0;
  }
  int s = i - 192512;
  if (s >= 0 && s < 64) { float iv = g1[s] / sqrtf(v1[s] + EPSB); sb1[s] = iv; sb1[64 + s] = b1[s] - m1[s] * iv; }
  if (s >= 64 && s < 128) { int c = s - 64; float iv = gk[c] / sqrtf(vk[c] + EPSB); sbk[c] = iv; sbk[64 + c] = bk[c] - mk[c] * iv; }
  if (s >= 128 && s < 384) { int c = s - 128; float iv = g2[c] / sqrtf(v2[c] + EPSB); sb2[c] = iv; sb2[256 + c] = b2[c] - m2[c] * iv; }
}

// ---------------- K1: 1x1 compress + BN + ReLU -> comp_t[n][52][52][64] bf16 -------
__global__ __launch_bounds__(256) void k_compress(
    const float* __restrict__ x, const unsigned short* __restrict__ wcb_t,
    const float* __restrict__ sb1, unsigned short* __restrict__ comp_t) {
  __shared__ unsigned short wl[16384];   // [ci][co] bf16
  int t = threadIdx.x;
  for (int f = t; f < 2048; f += 256)
    *(bf16x8*)&wl[f * 8] = *(const bf16x8*)&wcb_t[f * 8];
  __syncthreads();
  int idx = blockIdx.x * 256 + t;        // 73728
  int co2 = (idx & 31) * 2;
  int pg = idx >> 5;                     // 0..2303
  int n = pg / 1152;
  int pix0 = (pg % 1152) * 2;
  const float* xp = x + (size_t)n * 256 * 2304 + pix0;
  float a00 = 0.f, a01 = 0.f, a10 = 0.f, a11 = 0.f;
  for (int ci = 0; ci < 256; ++ci) {
    float2 xv = *(const float2*)(xp + (size_t)ci * 2304);
    unsigned pr = *(const unsigned*)&wl[ci * 64 + co2];
    union { unsigned u; float f; } wa, wb;
    wa.u = pr << 16; wb.u = pr & 0xffff0000u;
    a00 = fmaf(xv.x, wa.f, a00); a01 = fmaf(xv.y, wa.f, a01);
    a10 = fmaf(xv.x, wb.f, a10); a11 = fmaf(xv.y, wb.f, a11);
  }
  float s0 = sb1[co2], s1 = sb1[co2 + 1];
  float c0b = sb1[64 + co2], c1b = sb1[64 + co2 + 1];
  float o00 = fmaxf(fmaf(a00, s0, c0b), 0.f), o01 = fmaxf(fmaf(a01, s0, c0b), 0.f);
  float o10 = fmaxf(fmaf(a10, s1, c1b), 0.f), o11 = fmaxf(fmaf(a11, s1, c1b), 0.f);
  int r = pix0 / 48, c = pix0 % 48;
  unsigned short* ob = comp_t + ((size_t)n * 2704 + (r + 2) * 52 + (c + 2)) * 64 + co2;
  unsigned p0 = (unsigned)f2b(o00) | ((unsigned)f2b(o10) << 16);
  unsigned p1 = (unsigned)f2b(o01) | ((unsigned)f2b(o11) << 16);
  *(unsigned*)&ob[0]  = p0;
  *(unsigned*)&ob[64] = p1;
}

// ---------------- K2: 3x3 dil=2 conv via MFMA (K=576) + BN + ReLU -> k1_t ---------
__global__ __launch_bounds__(256) void k_ke1(
    const unsigned short* __restrict__ comp_t, const unsigned short* __restrict__ wt1,
    const float* __restrict__ sbk, unsigned short* __restrict__ k1_t) {
  __shared__ unsigned short sA[16640];   // 5 rows x 52 cols x 64 ci, XOR by col
  int t = threadIdx.x;
  int bid = blockIdx.x;                  // 96
  int n = bid / 48, y = bid % 48;
  const unsigned short* src = comp_t + ((size_t)n * 52 + y) * 52 * 64;
  for (int f = t; f < 2080; f += 256) {
    int g = f >> 3, ci0 = (f & 7) * 8;
    int cc = g % 52, rr = g / 52;
    bf16x8 vv = *(const bf16x8*)&src[(rr * 52 + cc) * 64 + ci0];
    int ba = (((rr * 52 + cc) * 64 + ci0) * 2) ^ ((cc & 7) << 4);
    *(bf16x8*)((char*)sA + ba) = vv;
  }
  __syncthreads();
  int wid = t >> 6, l = t & 63, l15 = l & 15, lg = l >> 4;
  f32x4 acc[3];
  acc[0] = acc[1] = acc[2] = (f32x4){0.f, 0.f, 0.f, 0.f};
  const unsigned short* arow = wt1 + (size_t)(wid * 16 + l15) * 576;
#pragma unroll
  for (int kbi = 0; kbi < 18; ++kbi) {
    int tap = kbi >> 1;
    int ky = tap / 3, kx = tap % 3;
    int ci0 = (kbi & 1) * 32 + lg * 8;
    bf16x8 afr = *(const bf16x8*)&arow[kbi * 32 + lg * 8];
#pragma unroll
    for (int nt = 0; nt < 3; ++nt) {
      int col = nt * 16 + l15 + 2 * kx;
      int ba = (((2 * ky * 52 + col) * 64 + ci0) * 2) ^ ((col & 7) << 4);
      bf16x8 bfr = *(const bf16x8*)((char*)sA + ba);
      acc[nt] = __builtin_amdgcn_mfma_f32_16x16x32_bf16(afr, bfr, acc[nt], 0, 0, 0);
    }
  }
  unsigned short* dst = k1_t + ((size_t)n * 50 + (y + 1)) * 50 * 64;
  int co0 = wid * 16 + lg * 4;
  float s0 = sbk[co0], s1 = sbk[co0 + 1], s2 = sbk[co0 + 2], s3 = sbk[co0 + 3];
  float d0 = sbk[64 + co0], d1 = sbk[64 + co0 + 1], d2 = sbk[64 + co0 + 2], d3 = sbk[64 + co0 + 3];
#pragma unroll
  for (int nt = 0; nt < 3; ++nt) {
    int px = nt * 16 + l15;
    ushort4 pk;
    pk.x = f2b(fmaxf(fmaf(acc[nt][0], s0, d0), 0.f));
    pk.y = f2b(fmaxf(fmaf(acc[nt][1], s1, d1), 0.f));
    pk.z = f2b(fmaxf(fmaf(acc[nt][2], s2, d2), 0.f));
    pk.w = f2b(fmaxf(fmaf(acc[nt][3], s3, d3), 0.f));
    *(ushort4*)&dst[(px + 1) * 64 + co0] = pk;
  }
}

// ---------------- K3: 3x3 conv via MFMA (K=576) -> kern_t[n][pix][112] fp32 -------
__global__ __launch_bounds__(256) void k_ke2(
    const unsigned short* __restrict__ k1_t, const unsigned short* __restrict__ wt2,
    float* __restrict__ kern_t) {
  __shared__ unsigned short sA[9600];    // 3 rows x 50 cols x 64 ci
  int t = threadIdx.x;
  int bid = blockIdx.x;                  // 96
  int n = bid / 48, y = bid % 48;
  const unsigned short* src = k1_t + ((size_t)n * 50 + y) * 50 * 64;
  for (int f = t; f < 1200; f += 256) {
    int g = f >> 3, ci0 = (f & 7) * 8;
    int cc = g % 50, rr = g / 50;
    bf16x8 vv = *(const bf16x8*)&src[(rr * 50 + cc) * 64 + ci0];
    int ba = (((rr * 50 + cc) * 64 + ci0) * 2) ^ ((cc & 7) << 4);
    *(bf16x8*)((char*)sA + ba) = vv;
  }
  __syncthreads();
  int wid = t >> 6, l = t & 63, l15 = l & 15, lg = l >> 4;
  f32x4 acc[2][3];
#pragma unroll
  for (int mi = 0; mi < 2; ++mi)
#pragma unroll
    for (int nt = 0; nt < 3; ++nt) acc[mi][nt] = (f32x4){0.f, 0.f, 0.f, 0.f};
#pragma unroll
  for (int kbi = 0; kbi < 18; ++kbi) {
    int tap = kbi >> 1;
    int ky = tap / 3, kx = tap % 3;
    int ci0 = (kbi & 1) * 32 + lg * 8;
    bf16x8 afr[2];
#pragma unroll
    for (int mi = 0; mi < 2; ++mi)
      afr[mi] = *(const bf16x8*)&wt2[(size_t)((wid * 2 + mi) * 16 + l15) * 576 + kbi * 32 + lg * 8];
#pragma unroll
    for (int nt = 0; nt < 3; ++nt) {
      int col = nt * 16 + l15 + kx;
      int ba = (((ky * 50 + col) * 64 + ci0) * 2) ^ ((col & 7) << 4);
      bf16x8 bfr = *(const bf16x8*)((char*)sA + ba);
      acc[0][nt] = __builtin_amdgcn_mfma_f32_16x16x32_bf16(afr[0], bfr, acc[0][nt], 0, 0, 0);
      acc[1][nt] = __builtin_amdgcn_mfma_f32_16x16x32_bf16(afr[1], bfr, acc[1][nt], 0, 0, 0);
    }
  }
#pragma unroll
  for (int mi = 0; mi < 2; ++mi) {
    int co0 = (wid * 2 + mi) * 16 + lg * 4;
    if (co0 < 100) {
#pragma unroll
      for (int nt = 0; nt < 3; ++nt) {
        int px = nt * 16 + l15;
        float4 vv = {acc[mi][nt][0], acc[mi][nt][1], acc[mi][nt][2], acc[mi][nt][3]};
        *(float4*)&kern_t[((size_t)n * 2304 + y * 48 + px) * 112 + co0] = vv;
      }
    }
  }
}

// ---------------- K4: fused softmax + bilinear + fold 25->9 ----------------------
__global__ __launch_bounds__(256) void k_w9sm(const float* __restrict__ kern_t,
                                              float* __restrict__ w9) {
  int idx = blockIdx.x * 256 + threadIdx.x;  // 73728
  int u = idx & 3;
  int w2 = (idx >> 2) % 96;
  int rest = (idx >> 2) / 96;
  int y96 = rest % 96;
  int n = rest / 96;
  float syf = fminf(fmaxf(y96 * 0.5f - 0.25f, 0.f), 47.f);
  int y0 = (int)syf; int y1 = min(y0 + 1, 47); float wy = syf - (float)y0;
  float sxf = fminf(fmaxf(w2 * 0.5f - 0.25f, 0.f), 47.f);
  int x0 = (int)sxf; int x1 = min(x0 + 1, 47); float wx = sxf - (float)x0;
  float bl[25];
#pragma unroll
  for (int k = 0; k < 25; ++k) bl[k] = 0.f;
  float ws4[4] = {(1.f - wx) * (1.f - wy), wx * (1.f - wy), (1.f - wx) * wy, wx * wy};
  int sy[4] = {y0, y0, y1, y1};
  int sx[4] = {x0, x1, x0, x1};
#pragma unroll
  for (int s = 0; s < 4; ++s) {
    const float* p = kern_t + ((size_t)n * 2304 + sy[s] * 48 + sx[s]) * 112 + u * 25;
    float vv[25], mx = -3.4e38f;
#pragma unroll
    for (int k = 0; k < 25; ++k) { vv[k] = p[k]; mx = fmaxf(mx, vv[k]); }
    float sum = 0.f;
#pragma unroll
    for (int k = 0; k < 25; ++k) { vv[k] = __expf(vv[k] - mx); sum += vv[k]; }
    float rs = ws4[s] / sum;
#pragma unroll
    for (int k = 0; k < 25; ++k) bl[k] = fmaf(vv[k], rs, bl[k]);
  }
#pragma unroll
  for (int kh = 0; kh < 5; ++kh) {
    bool vy = (unsigned)(y96 + kh - 2) < 96u;
#pragma unroll
    for (int kw = 0; kw < 5; ++kw) {
      bool vx = (unsigned)(w2 + kw - 2) < 96u;
      if (!(vy && vx)) bl[kh * 5 + kw] = 0.f;
    }
  }
  int py = y96 & 1, px_ = w2 & 1;
  float cc0[5], cc1[5], cc2[5];
#pragma unroll
  for (int kh = 0; kh < 5; ++kh) {
    cc0[kh] = px_ ? bl[kh * 5 + 0] : bl[kh * 5 + 0] + bl[kh * 5 + 1];
    cc1[kh] = px_ ? bl[kh * 5 + 1] + bl[kh * 5 + 2] : bl[kh * 5 + 2] + bl[kh * 5 + 3];
    cc2[kh] = px_ ? bl[kh * 5 + 3] + bl[kh * 5 + 4] : bl[kh * 5 + 4];
  }
  float* op = w9 + (((size_t)(n * 96 + y96) * 96 + w2) * 4 + u) * 9;
  op[0] = py ? cc0[0] : cc0[0] + cc0[1];
  op[1] = py ? cc1[0] : cc1[0] + cc1[1];
  op[2] = py ? cc2[0] : cc2[0] + cc2[1];
  op[3] = py ? cc0[1] + cc0[2] : cc0[2] + cc0[3];
  op[4] = py ? cc1[1] + cc1[2] : cc1[2] + cc1[3];
  op[5] = py ? cc2[1] + cc2[2] : cc2[2] + cc2[3];
  op[6] = py ? cc0[3] + cc0[4] : cc0[4];
  op[7] = py ? cc1[3] + cc1[4] : cc1[4];
  op[8] = py ? cc2[3] + cc2[4] : cc2[4];
}

// ---------------- K6 v2: y48-banded reassembly + MFMA proj + BN + ReLU -----------
__global__ __launch_bounds__(512) void k_reassemble_proj(
    const float* __restrict__ x, const float* __restrict__ w9,
    const unsigned short* __restrict__ pwb, const float* __restrict__ sb2,
    float* __restrict__ out) {
  __shared__ float xls[256 * 35];          // [parity(4)*64 + ch][3*11 pad 35]
  __shared__ float w9s[1152];              // [half(2)][16 w][4 u][9]
  __shared__ float sb2s[512];
  __shared__ unsigned short finT[128 * 256];

  int blk = blockIdx.x;                    // 576 = 2 * 48 * 6
  int n = blk / 288;
  int r = blk % 288;
  int y48 = r / 6;
  int xt = r % 6;
  int X0 = xt * 32;
  int x480 = xt * 8;
  int t = threadIdx.x;

  sb2s[t] = sb2[t];
  {
    const float* base = w9 + ((size_t)(n * 96 + 2 * y48) * 96 + xt * 16) * 36;
    for (int f = t; f < 1152; f += 512) {
      int half = f / 576, o = f - half * 576;
      w9s[f] = base[(size_t)half * 3456 + o];
    }
  }
  const float* xb = x + (size_t)n * 256 * 2304;
  for (int f = t; f < 8448; f += 512) {
    int c = f / 33, rc = f - c * 33;
    int ry = rc / 11, cx = rc - ry * 11;
    int sy = min(max(y48 + ry - 1, 0), 47);
    int sx = min(max(x480 + cx - 1, 0), 47);
    int slot = (c & 3) * 64 + (c >> 2);
    xls[slot * 35 + rc] = xb[(size_t)c * 2304 + sy * 48 + sx];
  }
  __syncthreads();

  // ---- phase 1: 9-tap reassembly for 4 Y rows x 32 X ----
  {
    int ci = t & 255;
    int half = t >> 8;                     // y96 row within band
    int u = ci >> 6, ch = ci & 63;
    int cb = ci >> 3, crr = ci & 7;
#pragma unroll
    for (int rY = 0; rY < 2; ++rY) {
      int Yl = half * 2 + rY;
      const float* xc0 = &xls[((rY * 2 + 0) * 64 + ch) * 35];
      const float* xc1 = &xls[((rY * 2 + 1) * 64 + ch) * 35];
      float xw0[9], xw1[9];
#pragma unroll
      for (int ry = 0; ry < 3; ++ry)
#pragma unroll
        for (int cx = 0; cx < 3; ++cx) {
          xw0[ry * 3 + cx] = xc0[ry * 11 + cx];
          xw1[ry * 3 + cx] = xc1[ry * 11 + cx];
        }
#pragma unroll
      for (int j = 0; j < 16; ++j) {
        if (j >= 2 && (j & 1) == 0) {
          int nc = (j >> 1) + 2;
#pragma unroll
          for (int ry = 0; ry < 3; ++ry) {
            xw0[ry*3+0]=xw0[ry*3+1]; xw0[ry*3+1]=xw0[ry*3+2]; xw0[ry*3+2]=xc0[ry*11+nc];
            xw1[ry*3+0]=xw1[ry*3+1]; xw1[ry*3+1]=xw1[ry*3+2]; xw1[ry*3+2]=xc1[ry*11+nc];
          }
        }
        const float* wt = &w9s[(half * 16 + j) * 36 + u * 9];
        float a0 = 0.f, a1 = 0.f;
#pragma unroll
        for (int k9 = 0; k9 < 9; ++k9) {
          float wv = wt[k9];
          a0 = fmaf(xw0[k9], wv, a0);
          a1 = fmaf(xw1[k9], wv, a1);
        }
        int px0 = Yl * 32 + 2 * j, px1 = px0 + 1;
        finT[px0 * 256 + ((cb ^ (px0 & 7)) * 8 + crr)] = f2b(a0);
        finT[px1 * 256 + ((cb ^ (px1 & 7)) * 8 + crr)] = f2b(a1);
      }
    }
  }
  __syncthreads();

  // ---- phase 2: MFMA  C[256 o][128 px] = pwb[256x256] @ fin[256][128] ----
  int wid = t >> 6, l = t & 63, l15 = l & 15, lg = l >> 4;
  f32x4 acc[2][8];
#pragma unroll
  for (int mi = 0; mi < 2; ++mi)
#pragma unroll
    for (int nt = 0; nt < 8; ++nt) acc[mi][nt] = (f32x4){0.f, 0.f, 0.f, 0.f};
  const unsigned short* a0p = pwb + (size_t)(wid * 2 * 16 + l15) * 256;
  const unsigned short* a1p = a0p + 16 * 256;
#pragma unroll
  for (int kbi = 0; kbi < 8; ++kbi) {
    bf16x8 afr0 = *(const bf16x8*)&a0p[kbi * 32 + lg * 8];
    bf16x8 afr1 = *(const bf16x8*)&a1p[kbi * 32 + lg * 8];
    int cbk = kbi * 4 + lg;
#pragma unroll
    for (int nt = 0; nt < 8; ++nt) {
      int row = nt * 16 + l15;
      bf16x8 bfr = *(const bf16x8*)&finT[row * 256 + ((cbk ^ (row & 7)) * 8)];
      acc[0][nt] = __builtin_amdgcn_mfma_f32_16x16x32_bf16(afr0, bfr, acc[0][nt], 0, 0, 0);
      acc[1][nt] = __builtin_amdgcn_mfma_f32_16x16x32_bf16(afr1, bfr, acc[1][nt], 0, 0, 0);
    }
  }
  size_t outn = (size_t)n * 256 * 36864;
  int Ybase = 4 * y48;
#pragma unroll
  for (int mi = 0; mi < 2; ++mi) {
    int mt = wid * 2 + mi;
#pragma unroll
    for (int r4 = 0; r4 < 4; ++r4) {
      int o = mt * 16 + lg * 4 + r4;
      float sc = sb2s[o], bi = sb2s[256 + o];
#pragma unroll
      for (int nt = 0; nt < 8; ++nt) {
        int px = nt * 16 + l15;
        int Yl = px >> 5, Xl = px & 31;
        float val = fmaxf(fmaf(acc[mi][nt][r4], sc, bi), 0.f);
        out[outn + (size_t)o * 36864 + (size_t)(Ybase + Yl) * 192 + X0 + Xl] = val;
      }
    }
  }
}

extern "C" void kernel_launch(void* const* d_in, const int* in_sizes, int n_in,
                              void* d_out, int out_size, void* d_ws, size_t ws_size,
                              hipStream_t stream) {
  const float* x   = (const float*)d_in[0];
  const float* cw  = (const float*)d_in[1];
  const float* g1  = (const float*)d_in[2];
  const float* b1  = (const float*)d_in[3];
  const float* m1  = (const float*)d_in[4];
  const float* v1  = (const float*)d_in[5];
  const float* k1w = (const float*)d_in[6];
  const float* gk  = (const float*)d_in[7];
  const float* bk  = (const float*)d_in[8];
  const float* mk  = (const float*)d_in[9];
  const float* vk  = (const float*)d_in[10];
  const float* k2w = (const float*)d_in[11];
  const float* pw  = (const float*)d_in[12];
  const float* g2  = (const float*)d_in[13];
  const float* b2  = (const float*)d_in[14];
  const float* m2  = (const float*)d_in[15];
  const float* v2  = (const float*)d_in[16];
  float* out = (float*)d_out;
  float* ws  = (float*)d_ws;

  unsigned short* comp_t = (unsigned short*)ws;            // 346112 bf16
  unsigned short* k1_t   = (unsigned short*)(ws + 173056); // 320000 bf16
  float* kern_t = ws + 333056;                             // 516096 f32
  float* w9     = ws + 849152;                             // 663552 f32
  unsigned short* pwb   = (unsigned short*)(ws + 1512704); // 65536 bf16
  unsigned short* wcb_t = (unsigned short*)(ws + 1545472); // 16384 bf16
  unsigned short* wt1   = (unsigned short*)(ws + 1553664); // 36864 bf16
  unsigned short* wt2   = (unsigned short*)(ws + 1572096); // 73728 bf16
  float* sb1 = ws + 1608960;                               // 128
  float* sbk = ws + 1609088;                               // 128
  float* sb2 = ws + 1609216;                               // 512

  hipMemsetAsync(comp_t, 0, 346112 * 2, stream);
  hipMemsetAsync(k1_t, 0, 320000 * 2, stream);

  k_prep<<<754, 256, 0, stream>>>(pw, cw, k1w, k2w, g1, b1, m1, v1,
                                  gk, bk, mk, vk, g2, b2, m2, v2,
                                  pwb, wcb_t, wt1, wt2, sb1, sbk, sb2);
  k_compress<<<288, 256, 0, stream>>>(x, wcb_t, sb1, comp_t);
  k_ke1<<<96, 256, 0, stream>>>(comp_t, wt1, sbk, k1_t);
  k_ke2<<<96, 256, 0, stream>>>(k1_t, wt2, kern_t);
  k_w9sm<<<288, 256, 0, stream>>>(kern_t, w9);
  k_reassemble_proj<<<576, 512, 0, stream>>>(x, w9, pwb, sb2, out);
}

// Round 4
// 202.007 us; speedup vs baseline: 8.2870x; 1.0452x over previous
//
#include <hip/hip_runtime.h>

#define EPSB 1e-5f

typedef __attribute__((ext_vector_type(8))) short bf16x8;
typedef __attribute__((ext_vector_type(4))) float f32x4;

__device__ __forceinline__ unsigned short f2b(float f) {
  union { float f; unsigned u; } cv; cv.f = f;
  unsigned r = cv.u + 0x7FFFu + ((cv.u >> 16) & 1u);
  return (unsigned short)(r >> 16);
}

// ---------------- K_prep: weight conversions/transposes + BN scale/bias + zero-fill ----
__global__ __launch_bounds__(256) void k_prep(
    const float* __restrict__ pw, const float* __restrict__ cw,
    const float* __restrict__ k1w, const float* __restrict__ k2w,
    const float* __restrict__ g1, const float* __restrict__ b1,
    const float* __restrict__ m1, const float* __restrict__ v1,
    const float* __restrict__ gk, const float* __restrict__ bk,
    const float* __restrict__ mk, const float* __restrict__ vk,
    const float* __restrict__ g2, const float* __restrict__ b2,
    const float* __restrict__ m2, const float* __restrict__ v2,
    unsigned short* __restrict__ pwb, unsigned short* __restrict__ wcb_t,
    unsigned short* __restrict__ wt1, unsigned short* __restrict__ wt2,
    float* __restrict__ sb1, float* __restrict__ sbk, float* __restrict__ sb2,
    float* __restrict__ wsz) {
  int i = blockIdx.x * 256 + threadIdx.x;
  if (i < 333056) wsz[i] = 0.f;           // zero comp_t + k1_t (incl. padded borders)
  if (i < 65536) pwb[i] = f2b(pw[i]);
  int j = i - 65536;
  if (j >= 0 && j < 16384) { int ci = j >> 6, co = j & 63; wcb_t[j] = f2b(cw[co * 256 + ci]); }
  int a = i - 81920;
  if (a >= 0 && a < 36864) {
    int co = a / 576, k = a % 576, tap = k >> 6, ci = k & 63;
    wt1[a] = f2b(k1w[co * 576 + ci * 9 + tap]);
  }
  int c2 = i - 118784;
  if (c2 >= 0 && c2 < 73728) {
    int co = c2 / 576, k = c2 % 576, tap = k >> 6, ci = k & 63;
    wt2[c2] = (co < 100) ? f2b(k2w[co * 576 + ci * 9 + tap]) : (unsigned short)0;
  }
  int s = i - 192512;
  if (s >= 0 && s < 64) { float iv = g1[s] / sqrtf(v1[s] + EPSB); sb1[s] = iv; sb1[64 + s] = b1[s] - m1[s] * iv; }
  if (s >= 64 && s < 128) { int c = s - 64; float iv = gk[c] / sqrtf(vk[c] + EPSB); sbk[c] = iv; sbk[64 + c] = bk[c] - mk[c] * iv; }
  if (s >= 128 && s < 384) { int c = s - 128; float iv = g2[c] / sqrtf(v2[c] + EPSB); sb2[c] = iv; sb2[256 + c] = b2[c] - m2[c] * iv; }
}

// ---------------- K1: 1x1 compress + BN + ReLU -> comp_t[n][52][52][64] bf16 -------
__global__ __launch_bounds__(256) void k_compress(
    const float* __restrict__ x, const unsigned short* __restrict__ wcb_t,
    const float* __restrict__ sb1, unsigned short* __restrict__ comp_t) {
  __shared__ unsigned short wl[16384];   // [ci][co] bf16
  int t = threadIdx.x;
  for (int f = t; f < 2048; f += 256)
    *(bf16x8*)&wl[f * 8] = *(const bf16x8*)&wcb_t[f * 8];
  __syncthreads();
  int idx = blockIdx.x * 256 + t;        // 73728
  int co2 = (idx & 31) * 2;
  int pg = idx >> 5;                     // 0..2303
  int n = pg / 1152;
  int pix0 = (pg % 1152) * 2;
  const float* xp = x + (size_t)n * 256 * 2304 + pix0;
  float a00 = 0.f, a01 = 0.f, a10 = 0.f, a11 = 0.f;
  for (int ci = 0; ci < 256; ++ci) {
    float2 xv = *(const float2*)(xp + (size_t)ci * 2304);
    unsigned pr = *(const unsigned*)&wl[ci * 64 + co2];
    union { unsigned u; float f; } wa, wb;
    wa.u = pr << 16; wb.u = pr & 0xffff0000u;
    a00 = fmaf(xv.x, wa.f, a00); a01 = fmaf(xv.y, wa.f, a01);
    a10 = fmaf(xv.x, wb.f, a10); a11 = fmaf(xv.y, wb.f, a11);
  }
  float s0 = sb1[co2], s1 = sb1[co2 + 1];
  float c0b = sb1[64 + co2], c1b = sb1[64 + co2 + 1];
  float o00 = fmaxf(fmaf(a00, s0, c0b), 0.f), o01 = fmaxf(fmaf(a01, s0, c0b), 0.f);
  float o10 = fmaxf(fmaf(a10, s1, c1b), 0.f), o11 = fmaxf(fmaf(a11, s1, c1b), 0.f);
  int r = pix0 / 48, c = pix0 % 48;
  unsigned short* ob = comp_t + ((size_t)n * 2704 + (r + 2) * 52 + (c + 2)) * 64 + co2;
  unsigned p0 = (unsigned)f2b(o00) | ((unsigned)f2b(o10) << 16);
  unsigned p1 = (unsigned)f2b(o01) | ((unsigned)f2b(o11) << 16);
  *(unsigned*)&ob[0]  = p0;
  *(unsigned*)&ob[64] = p1;
}

// ---------------- K2: 3x3 dil=2 conv via MFMA (K=576) + BN + ReLU -> k1_t ---------
__global__ __launch_bounds__(256) void k_ke1(
    const unsigned short* __restrict__ comp_t, const unsigned short* __restrict__ wt1,
    const float* __restrict__ sbk, unsigned short* __restrict__ k1_t) {
  __shared__ unsigned short sA[16640];   // 5 rows x 52 cols x 64 ci, XOR by col
  int t = threadIdx.x;
  int bid = blockIdx.x;                  // 96
  int n = bid / 48, y = bid % 48;
  const unsigned short* src = comp_t + ((size_t)n * 52 + y) * 52 * 64;
  for (int f = t; f < 2080; f += 256) {
    int g = f >> 3, ci0 = (f & 7) * 8;
    int cc = g % 52, rr = g / 52;
    bf16x8 vv = *(const bf16x8*)&src[(rr * 52 + cc) * 64 + ci0];
    int ba = (((rr * 52 + cc) * 64 + ci0) * 2) ^ ((cc & 7) << 4);
    *(bf16x8*)((char*)sA + ba) = vv;
  }
  __syncthreads();
  int wid = t >> 6, l = t & 63, l15 = l & 15, lg = l >> 4;
  f32x4 acc[3];
  acc[0] = acc[1] = acc[2] = (f32x4){0.f, 0.f, 0.f, 0.f};
  const unsigned short* arow = wt1 + (size_t)(wid * 16 + l15) * 576;
#pragma unroll
  for (int kbi = 0; kbi < 18; ++kbi) {
    int tap = kbi >> 1;
    int ky = tap / 3, kx = tap % 3;
    int ci0 = (kbi & 1) * 32 + lg * 8;
    bf16x8 afr = *(const bf16x8*)&arow[kbi * 32 + lg * 8];
#pragma unroll
    for (int nt = 0; nt < 3; ++nt) {
      int col = nt * 16 + l15 + 2 * kx;
      int ba = (((2 * ky * 52 + col) * 64 + ci0) * 2) ^ ((col & 7) << 4);
      bf16x8 bfr = *(const bf16x8*)((char*)sA + ba);
      acc[nt] = __builtin_amdgcn_mfma_f32_16x16x32_bf16(afr, bfr, acc[nt], 0, 0, 0);
    }
  }
  unsigned short* dst = k1_t + ((size_t)n * 50 + (y + 1)) * 50 * 64;
  int co0 = wid * 16 + lg * 4;
  float s0 = sbk[co0], s1 = sbk[co0 + 1], s2 = sbk[co0 + 2], s3 = sbk[co0 + 3];
  float d0 = sbk[64 + co0], d1 = sbk[64 + co0 + 1], d2 = sbk[64 + co0 + 2], d3 = sbk[64 + co0 + 3];
#pragma unroll
  for (int nt = 0; nt < 3; ++nt) {
    int px = nt * 16 + l15;
    ushort4 pk;
    pk.x = f2b(fmaxf(fmaf(acc[nt][0], s0, d0), 0.f));
    pk.y = f2b(fmaxf(fmaf(acc[nt][1], s1, d1), 0.f));
    pk.z = f2b(fmaxf(fmaf(acc[nt][2], s2, d2), 0.f));
    pk.w = f2b(fmaxf(fmaf(acc[nt][3], s3, d3), 0.f));
    *(ushort4*)&dst[(px + 1) * 64 + co0] = pk;
  }
}

// ---------------- K3: 3x3 conv via MFMA (K=576) -> kern_t[n][pix][112] fp32 -------
__global__ __launch_bounds__(256) void k_ke2(
    const unsigned short* __restrict__ k1_t, const unsigned short* __restrict__ wt2,
    float* __restrict__ kern_t) {
  __shared__ unsigned short sA[9600];    // 3 rows x 50 cols x 64 ci
  int t = threadIdx.x;
  int bid = blockIdx.x;                  // 96
  int n = bid / 48, y = bid % 48;
  const unsigned short* src = k1_t + ((size_t)n * 50 + y) * 50 * 64;
  for (int f = t; f < 1200; f += 256) {
    int g = f >> 3, ci0 = (f & 7) * 8;
    int cc = g % 50, rr = g / 50;
    bf16x8 vv = *(const bf16x8*)&src[(rr * 50 + cc) * 64 + ci0];
    int ba = (((rr * 50 + cc) * 64 + ci0) * 2) ^ ((cc & 7) << 4);
    *(bf16x8*)((char*)sA + ba) = vv;
  }
  __syncthreads();
  int wid = t >> 6, l = t & 63, l15 = l & 15, lg = l >> 4;
  f32x4 acc[2][3];
#pragma unroll
  for (int mi = 0; mi < 2; ++mi)
#pragma unroll
    for (int nt = 0; nt < 3; ++nt) acc[mi][nt] = (f32x4){0.f, 0.f, 0.f, 0.f};
#pragma unroll
  for (int kbi = 0; kbi < 18; ++kbi) {
    int tap = kbi >> 1;
    int ky = tap / 3, kx = tap % 3;
    int ci0 = (kbi & 1) * 32 + lg * 8;
    bf16x8 afr[2];
#pragma unroll
    for (int mi = 0; mi < 2; ++mi)
      afr[mi] = *(const bf16x8*)&wt2[(size_t)((wid * 2 + mi) * 16 + l15) * 576 + kbi * 32 + lg * 8];
#pragma unroll
    for (int nt = 0; nt < 3; ++nt) {
      int col = nt * 16 + l15 + kx;
      int ba = (((ky * 50 + col) * 64 + ci0) * 2) ^ ((col & 7) << 4);
      bf16x8 bfr = *(const bf16x8*)((char*)sA + ba);
      acc[0][nt] = __builtin_amdgcn_mfma_f32_16x16x32_bf16(afr[0], bfr, acc[0][nt], 0, 0, 0);
      acc[1][nt] = __builtin_amdgcn_mfma_f32_16x16x32_bf16(afr[1], bfr, acc[1][nt], 0, 0, 0);
    }
  }
#pragma unroll
  for (int mi = 0; mi < 2; ++mi) {
    int co0 = (wid * 2 + mi) * 16 + lg * 4;
    if (co0 < 100) {
#pragma unroll
      for (int nt = 0; nt < 3; ++nt) {
        int px = nt * 16 + l15;
        float4 vv = {acc[mi][nt][0], acc[mi][nt][1], acc[mi][nt][2], acc[mi][nt][3]};
        *(float4*)&kern_t[((size_t)n * 2304 + y * 48 + px) * 112 + co0] = vv;
      }
    }
  }
}

// ---------------- K4 v2: LDS-staged softmax + bilinear + fold 25->9 ----------------
// block = (n, y48 k); stages kern_t rows {max(k-1,0), k, min(k+1,47)}
__global__ __launch_bounds__(256) void k_w9sm(const float* __restrict__ kern_t,
                                              float* __restrict__ w9) {
  __shared__ float ks[3 * 48 * 116];     // [slot][sx][116 pad]
  int bid = blockIdx.x;                  // 96
  int n = bid / 48, k = bid % 48;
  int t = threadIdx.x;
  int rows[3] = {max(k - 1, 0), k, min(k + 1, 47)};
#pragma unroll
  for (int s = 0; s < 3; ++s) {
    const float* src = kern_t + ((size_t)n * 2304 + rows[s] * 48) * 112;
    for (int f = t; f < 1344; f += 256) {
      float4 vv = *(const float4*)&src[f * 4];
      int sx = f / 28, c = (f % 28) * 4;
      *(float4*)&ks[(s * 48 + sx) * 116 + c] = vv;
    }
  }
  __syncthreads();
#pragma unroll
  for (int it = 0; it < 3; ++it) {
    int f = t + it * 256;                // 0..767
    int half = f / 384, rem = f % 384;
    int w2 = rem >> 2, u = rem & 3;
    int y96 = 2 * k + half;
    float syf = fminf(fmaxf(y96 * 0.5f - 0.25f, 0.f), 47.f);
    int y0 = (int)syf; int y1 = min(y0 + 1, 47); float wy = syf - (float)y0;
    int sl0 = (y0 == k) ? 1 : 0;
    int sl1 = (y1 == k) ? 1 : 2;
    float sxf = fminf(fmaxf(w2 * 0.5f - 0.25f, 0.f), 47.f);
    int x0 = (int)sxf; int x1 = min(x0 + 1, 47); float wx = sxf - (float)x0;
    float bl[25];
#pragma unroll
    for (int kk = 0; kk < 25; ++kk) bl[kk] = 0.f;
    float ws4[4] = {(1.f - wx) * (1.f - wy), wx * (1.f - wy), (1.f - wx) * wy, wx * wy};
    int ssy[4] = {sl0, sl0, sl1, sl1};
    int ssx[4] = {x0, x1, x0, x1};
#pragma unroll
    for (int s = 0; s < 4; ++s) {
      const float* p = &ks[(ssy[s] * 48 + ssx[s]) * 116 + u * 25];
      float vv[25], mx = -3.4e38f;
#pragma unroll
      for (int kk = 0; kk < 25; ++kk) { vv[kk] = p[kk]; mx = fmaxf(mx, vv[kk]); }
      float sum = 0.f;
#pragma unroll
      for (int kk = 0; kk < 25; ++kk) { vv[kk] = __expf(vv[kk] - mx); sum += vv[kk]; }
      float rs = ws4[s] / sum;
#pragma unroll
      for (int kk = 0; kk < 25; ++kk) bl[kk] = fmaf(vv[kk], rs, bl[kk]);
    }
#pragma unroll
    for (int kh = 0; kh < 5; ++kh) {
      bool vy = (unsigned)(y96 + kh - 2) < 96u;
#pragma unroll
      for (int kw = 0; kw < 5; ++kw) {
        bool vx = (unsigned)(w2 + kw - 2) < 96u;
        if (!(vy && vx)) bl[kh * 5 + kw] = 0.f;
      }
    }
    int py = y96 & 1, px_ = w2 & 1;
    float cc0[5], cc1[5], cc2[5];
#pragma unroll
    for (int kh = 0; kh < 5; ++kh) {
      cc0[kh] = px_ ? bl[kh * 5 + 0] : bl[kh * 5 + 0] + bl[kh * 5 + 1];
      cc1[kh] = px_ ? bl[kh * 5 + 1] + bl[kh * 5 + 2] : bl[kh * 5 + 2] + bl[kh * 5 + 3];
      cc2[kh] = px_ ? bl[kh * 5 + 3] + bl[kh * 5 + 4] : bl[kh * 5 + 4];
    }
    float* op = w9 + (((size_t)(n * 96 + y96) * 96 + w2) * 4 + u) * 9;
    op[0] = py ? cc0[0] : cc0[0] + cc0[1];
    op[1] = py ? cc1[0] : cc1[0] + cc1[1];
    op[2] = py ? cc2[0] : cc2[0] + cc2[1];
    op[3] = py ? cc0[1] + cc0[2] : cc0[2] + cc0[3];
    op[4] = py ? cc1[1] + cc1[2] : cc1[2] + cc1[3];
    op[5] = py ? cc2[1] + cc2[2] : cc2[2] + cc2[3];
    op[6] = py ? cc0[3] + cc0[4] : cc0[4];
    op[7] = py ? cc1[3] + cc1[4] : cc1[4];
    op[8] = py ? cc2[3] + cc2[4] : cc2[4];
  }
}

// ---------------- K6 v3: chunked reassembly + MFMA proj, 2 blocks/CU, no spill ----
__global__ __launch_bounds__(512, 4) void k_reassemble_proj(
    const float* __restrict__ x, const float* __restrict__ w9,
    const unsigned short* __restrict__ pwb, const float* __restrict__ sb2,
    float* __restrict__ out) {
  __shared__ float xls[256 * 35];          // [parity(4)*64 + ch][3*11 pad 35]
  __shared__ float w9s[1152];              // [half(2)][16 w][4 u][9]
  __shared__ float sb2s[512];
  __shared__ unsigned short finT[64 * 256];// 64 px chunk x 256 ci, swizzled

  int blk = blockIdx.x;                    // 576 = 2 * 48 * 6
  int n = blk / 288;
  int r = blk % 288;
  int y48 = r / 6;
  int xt = r % 6;
  int X0 = xt * 32;
  int x480 = xt * 8;
  int t = threadIdx.x;

  sb2s[t] = sb2[t];
  {
    const float* base = w9 + ((size_t)(n * 96 + 2 * y48) * 96 + xt * 16) * 36;
    for (int f = t; f < 1152; f += 512) {
      int half = f / 576, o = f - half * 576;
      w9s[f] = base[(size_t)half * 3456 + o];
    }
  }
  const float* xb = x + (size_t)n * 256 * 2304;
  for (int f = t; f < 8448; f += 512) {
    int c = f / 33, rc = f - c * 33;
    int ry = rc / 11, cx = rc - ry * 11;
    int sy = min(max(y48 + ry - 1, 0), 47);
    int sx = min(max(x480 + cx - 1, 0), 47);
    int slot = (c & 3) * 64 + (c >> 2);
    xls[slot * 35 + rc] = xb[(size_t)c * 2304 + sy * 48 + sx];
  }
  __syncthreads();

  int ci = t & 255, rY = t >> 8;           // rY = parity row within chunk
  int u = ci >> 6, ch = ci & 63;
  int cb = ci >> 3, crr = ci & 7;
  int wid = t >> 6, l = t & 63, l15 = l & 15, lg = l >> 4;
  const unsigned short* a0p = pwb + (size_t)(wid * 2 * 16 + l15) * 256;
  const unsigned short* a1p = a0p + 16 * 256;
  size_t outn = (size_t)n * 256 * 36864;
  int Ybase = 4 * y48;

#pragma unroll
  for (int chunk = 0; chunk < 2; ++chunk) {
    // ---- phase 1: 9-tap reassembly for 2 Y rows x 32 X -> finT ----
    {
      const float* xc0 = &xls[((rY * 2 + 0) * 64 + ch) * 35];
      const float* xc1 = &xls[((rY * 2 + 1) * 64 + ch) * 35];
      float xw0[9], xw1[9];
#pragma unroll
      for (int ry = 0; ry < 3; ++ry)
#pragma unroll
        for (int cx = 0; cx < 3; ++cx) {
          xw0[ry * 3 + cx] = xc0[ry * 11 + cx];
          xw1[ry * 3 + cx] = xc1[ry * 11 + cx];
        }
#pragma unroll
      for (int j = 0; j < 16; ++j) {
        if (j >= 2 && (j & 1) == 0) {
          int nc = (j >> 1) + 2;
#pragma unroll
          for (int ry = 0; ry < 3; ++ry) {
            xw0[ry*3+0]=xw0[ry*3+1]; xw0[ry*3+1]=xw0[ry*3+2]; xw0[ry*3+2]=xc0[ry*11+nc];
            xw1[ry*3+0]=xw1[ry*3+1]; xw1[ry*3+1]=xw1[ry*3+2]; xw1[ry*3+2]=xc1[ry*11+nc];
          }
        }
        const float* wt = &w9s[(chunk * 16 + j) * 36 + u * 9];
        float a0 = 0.f, a1 = 0.f;
#pragma unroll
        for (int k9 = 0; k9 < 9; ++k9) {
          float wv = wt[k9];
          a0 = fmaf(xw0[k9], wv, a0);
          a1 = fmaf(xw1[k9], wv, a1);
        }
        int px0 = rY * 32 + 2 * j, px1 = px0 + 1;
        finT[px0 * 256 + ((cb ^ (px0 & 7)) * 8 + crr)] = f2b(a0);
        finT[px1 * 256 + ((cb ^ (px1 & 7)) * 8 + crr)] = f2b(a1);
      }
    }
    __syncthreads();

    // ---- phase 2: MFMA  C[256 o][64 px] = pwb @ finT ----
    f32x4 acc[2][4];
#pragma unroll
    for (int mi = 0; mi < 2; ++mi)
#pragma unroll
      for (int nt = 0; nt < 4; ++nt) acc[mi][nt] = (f32x4){0.f, 0.f, 0.f, 0.f};
#pragma unroll
    for (int kbi = 0; kbi < 8; ++kbi) {
      bf16x8 afr0 = *(const bf16x8*)&a0p[kbi * 32 + lg * 8];
      bf16x8 afr1 = *(const bf16x8*)&a1p[kbi * 32 + lg * 8];
      int cbk = kbi * 4 + lg;
#pragma unroll
      for (int nt = 0; nt < 4; ++nt) {
        int row = nt * 16 + l15;
        bf16x8 bfr = *(const bf16x8*)&finT[row * 256 + ((cbk ^ (row & 7)) * 8)];
        acc[0][nt] = __builtin_amdgcn_mfma_f32_16x16x32_bf16(afr0, bfr, acc[0][nt], 0, 0, 0);
        acc[1][nt] = __builtin_amdgcn_mfma_f32_16x16x32_bf16(afr1, bfr, acc[1][nt], 0, 0, 0);
      }
    }
#pragma unroll
    for (int mi = 0; mi < 2; ++mi) {
      int mt = wid * 2 + mi;
#pragma unroll
      for (int r4 = 0; r4 < 4; ++r4) {
        int o = mt * 16 + lg * 4 + r4;
        float sc = sb2s[o], bi = sb2s[256 + o];
#pragma unroll
        for (int nt = 0; nt < 4; ++nt) {
          int px = nt * 16 + l15;
          int Yl = chunk * 2 + (px >> 5), Xl = px & 31;
          float val = fmaxf(fmaf(acc[mi][nt][r4], sc, bi), 0.f);
          out[outn + (size_t)o * 36864 + (size_t)(Ybase + Yl) * 192 + X0 + Xl] = val;
        }
      }
    }
    __syncthreads();   // protect finT before next chunk's phase 1
  }
}

extern "C" void kernel_launch(void* const* d_in, const int* in_sizes, int n_in,
                              void* d_out, int out_size, void* d_ws, size_t ws_size,
                              hipStream_t stream) {
  const float* x   = (const float*)d_in[0];
  const float* cw  = (const float*)d_in[1];
  const float* g1  = (const float*)d_in[2];
  const float* b1  = (const float*)d_in[3];
  const float* m1  = (const float*)d_in[4];
  const float* v1  = (const float*)d_in[5];
  const float* k1w = (const float*)d_in[6];
  const float* gk  = (const float*)d_in[7];
  const float* bk  = (const float*)d_in[8];
  const float* mk  = (const float*)d_in[9];
  const float* vk  = (const float*)d_in[10];
  const float* k2w = (const float*)d_in[11];
  const float* pw  = (const float*)d_in[12];
  const float* g2  = (const float*)d_in[13];
  const float* b2  = (const float*)d_in[14];
  const float* m2  = (const float*)d_in[15];
  const float* v2  = (const float*)d_in[16];
  float* out = (float*)d_out;
  float* ws  = (float*)d_ws;

  unsigned short* comp_t = (unsigned short*)ws;            // 346112 bf16
  unsigned short* k1_t   = (unsigned short*)(ws + 173056); // 320000 bf16
  float* kern_t = ws + 333056;                             // 516096 f32
  float* w9     = ws + 849152;                             // 663552 f32
  unsigned short* pwb   = (unsigned short*)(ws + 1512704); // 65536 bf16
  unsigned short* wcb_t = (unsigned short*)(ws + 1545472); // 16384 bf16
  unsigned short* wt1   = (unsigned short*)(ws + 1553664); // 36864 bf16
  unsigned short* wt2   = (unsigned short*)(ws + 1572096); // 73728 bf16
  float* sb1 = ws + 1608960;                               // 128
  float* sbk = ws + 1609088;                               // 128
  float* sb2 = ws + 1609216;                               // 512

  k_prep<<<1302, 256, 0, stream>>>(pw, cw, k1w, k2w, g1, b1, m1, v1,
                                   gk, bk, mk, vk, g2, b2, m2, v2,
                                   pwb, wcb_t, wt1, wt2, sb1, sbk, sb2, ws);
  k_compress<<<288, 256, 0, stream>>>(x, wcb_t, sb1, comp_t);
  k_ke1<<<96, 256, 0, stream>>>(comp_t, wt1, sbk, k1_t);
  k_ke2<<<96, 256, 0, stream>>>(k1_t, wt2, kern_t);
  k_w9sm<<<96, 256, 0, stream>>>(kern_t, w9);
  k_reassemble_proj<<<576, 512, 0, stream>>>(x, w9, pwb, sb2, out);
}